// Round 1
// baseline (39.965 us; speedup 1.0000x reference)
//
#include <hip/hip_runtime.h>

// 3x3 median filter, reflect padding, fp32.
// Input/output: (B=4, C=3, H=1024, W=1024) fp32, NCHW contiguous.
// One block per (plane,row); 256 threads x 4 pixels (float4) per thread.

#define S2(a, b) { float _t = fminf(a, b); b = fmaxf(a, b); a = _t; }
#define MN3(a, b, c) S2(a, b); S2(a, c);
#define MX3(a, b, c) S2(b, c); S2(a, c);
#define MNMX3(a, b, c) MX3(a, b, c); S2(a, b);
#define MNMX4(a, b, c, d) S2(a, b); S2(c, d); S2(a, c); S2(b, d);
#define MNMX5(a, b, c, d, e) S2(a, b); S2(c, d); MN3(a, c, e); MX3(b, d, e);
#define MNMX6(a, b, c, d, e, f) S2(a, d); S2(b, e); S2(c, f); MN3(a, b, c); MX3(d, e, f);

__global__ __launch_bounds__(256) void median3x3_kernel(
    const float* __restrict__ in, float* __restrict__ out, int H, int W) {
  const int plane = blockIdx.y;      // B*C plane index
  const int y     = blockIdx.x;      // row
  const int x0    = threadIdx.x * 4; // first pixel of this thread's 4
  if (x0 >= W) return;

  const float* p = in + (size_t)plane * H * W;

  // reflect rows: -1 -> 1, H -> H-2
  const int ym = (y == 0) ? 1 : y - 1;
  const int yp = (y == H - 1) ? H - 2 : y + 1;
  const int rows[3] = {ym, y, yp};

  // v[r] = [left_halo, m0, m1, m2, m3, right_halo]
  float v[3][6];
  #pragma unroll
  for (int r = 0; r < 3; ++r) {
    const float* rp = p + (size_t)rows[r] * W;
    const float4 m = *reinterpret_cast<const float4*>(rp + x0);
    v[r][1] = m.x; v[r][2] = m.y; v[r][3] = m.z; v[r][4] = m.w;
    // reflect cols: -1 -> 1 (== m.y when x0==0), W -> W-2 (== m.z when x0+4==W)
    v[r][0] = (x0 == 0)      ? m.y : rp[x0 - 1];
    v[r][5] = (x0 + 4 >= W)  ? m.z : rp[x0 + 4];
  }

  float4 o;
  float* op = &o.x;
  #pragma unroll
  for (int i = 0; i < 4; ++i) {
    // 9-element window for pixel x0+i
    float p0 = v[0][i], p1 = v[0][i + 1], p2 = v[0][i + 2];
    float p3 = v[1][i], p4 = v[1][i + 1], p5 = v[1][i + 2];
    float p6 = v[2][i], p7 = v[2][i + 1], p8 = v[2][i + 2];
    // McGuire median-of-9 (20 exchanges); median lands in p4
    MNMX6(p0, p1, p2, p3, p4, p5);
    MNMX5(p1, p2, p3, p4, p6);
    MNMX4(p2, p3, p4, p7);
    MNMX3(p3, p4, p8);
    op[i] = p4;
  }

  *reinterpret_cast<float4*>(out + (size_t)plane * H * W + (size_t)y * W + x0) = o;
}

extern "C" void kernel_launch(void* const* d_in, const int* in_sizes, int n_in,
                              void* d_out, int out_size, void* d_ws, size_t ws_size,
                              hipStream_t stream) {
  const float* x = (const float*)d_in[0];
  float* out = (float*)d_out;

  const int H = 1024, W = 1024;
  const int planes = in_sizes[0] / (H * W);  // B*C = 12

  dim3 grid(H, planes);
  dim3 block(W / 4);  // 256 threads, 4 px each
  median3x3_kernel<<<grid, block, 0, stream>>>(x, out, H, W);
}

// Round 2
// 22.802 us; speedup vs baseline: 1.7527x; 1.7527x over previous
//
#include <hip/hip_runtime.h>

// 3x3 median filter, reflect padding, fp32, NCHW (4,3,1024,1024).
// Block = 256 threads = full 1024-wide row (4 px/thread as float4),
// each block computes R=8 consecutive rows with a 3-row register rolling
// window (one new row load per output row -> read amp (R+2)/R = 1.25x).
// Halo pixels via __shfl within the wave; scalar loads only at wave edges.
// Median-of-9 via column decomposition: per column sort the vertical
// triple (lo,mi,hi), then median = med3(max3(lo), med3(mi), min3(hi)).

constexpr int R = 8;

__device__ __forceinline__ float med3(float a, float b, float c) {
  return fmaxf(fminf(a, b), fminf(fmaxf(a, b), c));
}

__global__ __launch_bounds__(256) void median3x3_kernel(
    const float* __restrict__ in, float* __restrict__ out, int H, int W) {
  const int plane = blockIdx.y;
  const int y0    = blockIdx.x * R;
  const int tid   = threadIdx.x;
  const int x0    = tid * 4;
  const int lane  = tid & 63;

  const float* p = in  + (size_t)plane * H * W;
  float*       q = out + (size_t)plane * H * W;

  float rows[3][6];  // rolling window: [left_halo, m0..m3, right_halo]

  auto load_row = [&](int y, float (&v)[6]) {
    const float* rp = p + (size_t)y * W;
    const float4 m = *reinterpret_cast<const float4*>(rp + x0);
    float lh = __shfl_up(m.w, 1);    // left neighbor's last px (wave-internal)
    float rh = __shfl_down(m.x, 1);  // right neighbor's first px
    if (lane == 0)  lh = (x0 == 0)     ? m.y : rp[x0 - 1];  // reflect or cross-wave
    if (lane == 63) rh = (x0 + 4 >= W) ? m.z : rp[x0 + 4];
    v[0] = lh; v[1] = m.x; v[2] = m.y; v[3] = m.z; v[4] = m.w; v[5] = rh;
  };

  // prime: row y0-1 (reflect: -1 -> 1) and row y0
  load_row(y0 == 0 ? 1 : y0 - 1, rows[0]);
  load_row(y0, rows[1]);

  #pragma unroll
  for (int r = 0; r < R; ++r) {
    const int y  = y0 + r;
    const int yn = (y == H - 1) ? H - 2 : y + 1;  // reflect: H -> H-2
    load_row(yn, rows[(r + 2) % 3]);

    const float (&a)[6] = rows[r % 3];
    const float (&b)[6] = rows[(r + 1) % 3];
    const float (&c)[6] = rows[(r + 2) % 3];

    // per-column sorted vertical triple (non-destructive)
    float lo[6], mi[6], hi[6];
    #pragma unroll
    for (int j = 0; j < 6; ++j) {
      const float plo = fminf(b[j], c[j]);
      const float phi = fmaxf(b[j], c[j]);
      lo[j] = fminf(a[j], plo);
      hi[j] = fmaxf(a[j], phi);
      mi[j] = fmaxf(plo, fminf(a[j], phi));
    }

    float4 o;
    float* op = &o.x;
    #pragma unroll
    for (int i = 0; i < 4; ++i) {
      const float mxlo = fmaxf(fmaxf(lo[i], lo[i + 1]), lo[i + 2]);
      const float mnhi = fminf(fminf(hi[i], hi[i + 1]), hi[i + 2]);
      const float mdmi = med3(mi[i], mi[i + 1], mi[i + 2]);
      op[i] = med3(mxlo, mdmi, mnhi);
    }
    *reinterpret_cast<float4*>(q + (size_t)y * W + x0) = o;
  }
}

extern "C" void kernel_launch(void* const* d_in, const int* in_sizes, int n_in,
                              void* d_out, int out_size, void* d_ws, size_t ws_size,
                              hipStream_t stream) {
  const float* x = (const float*)d_in[0];
  float* out = (float*)d_out;

  const int H = 1024, W = 1024;
  const int planes = in_sizes[0] / (H * W);  // B*C = 12

  dim3 grid(H / R, planes);   // (128, 12)
  dim3 block(W / 4);          // 256 threads, 4 px each
  median3x3_kernel<<<grid, block, 0, stream>>>(x, out, H, W);
}

// Round 4
// 22.027 us; speedup vs baseline: 1.8144x; 1.0352x over previous
//
#include <hip/hip_runtime.h>

// 3x3 median filter, reflect padding, fp32, NCHW (4,3,1024,1024).
// 256 threads = full 1024-wide row (4 px/thread as float4); each block
// computes R=16 consecutive rows via a 3-row register rolling window
// (read amp (R+2)/R = 1.125x). Halos via __shfl inside the wave.
// XCD-chunked block swizzle keeps vertically-adjacent blocks (which share
// halo rows) on the same XCD L2. Nontemporal stores keep the write stream
// out of L2 so input rows stay resident for vertical reuse.
// Median-of-9 = column decomposition: med3(max3(lo), med3(mi), min3(hi)).

constexpr int R = 16;
constexpr int NXCD = 8;

typedef float f32x4 __attribute__((ext_vector_type(4)));  // nontemporal-storable

__device__ __forceinline__ float med3(float a, float b, float c) {
  return __builtin_amdgcn_fmed3f(a, b, c);
}

__global__ __launch_bounds__(256) void median3x3_kernel(
    const float* __restrict__ in, float* __restrict__ out, int H, int W,
    int tiles_per_plane, int chunk) {
  // XCD-chunked swizzle: default dispatch round-robins blockIdx.x across
  // XCDs; remap so each XCD owns a contiguous run of row-tiles.
  const int wg  = blockIdx.x;
  const int swz = (wg & (NXCD - 1)) * chunk + (wg >> 3);
  const int plane = swz / tiles_per_plane;
  const int y0    = (swz % tiles_per_plane) * R;

  const int tid  = threadIdx.x;
  const int x0   = tid * 4;
  const int lane = tid & 63;

  const float* p = in  + (size_t)plane * H * W;
  float*       q = out + (size_t)plane * H * W;

  float rows[3][6];  // rolling window: [left_halo, m0..m3, right_halo]

  auto load_row = [&](int y, float (&v)[6]) {
    const float* rp = p + (size_t)y * W;
    const float4 m = *reinterpret_cast<const float4*>(rp + x0);
    float lh = __shfl_up(m.w, 1);    // left neighbor's last px
    float rh = __shfl_down(m.x, 1);  // right neighbor's first px
    if (lane == 0)  lh = (x0 == 0)     ? m.y : rp[x0 - 1];  // reflect / cross-wave
    if (lane == 63) rh = (x0 + 4 >= W) ? m.z : rp[x0 + 4];
    v[0] = lh; v[1] = m.x; v[2] = m.y; v[3] = m.z; v[4] = m.w; v[5] = rh;
  };

  // prime: row y0-1 (reflect: -1 -> 1) and row y0
  load_row(y0 == 0 ? 1 : y0 - 1, rows[0]);
  load_row(y0, rows[1]);

  #pragma unroll
  for (int r = 0; r < R; ++r) {
    const int y  = y0 + r;
    const int yn = (y == H - 1) ? H - 2 : y + 1;  // reflect: H -> H-2
    load_row(yn, rows[(r + 2) % 3]);

    const float (&a)[6] = rows[r % 3];
    const float (&b)[6] = rows[(r + 1) % 3];
    const float (&c)[6] = rows[(r + 2) % 3];

    // per-column sorted vertical triple (non-destructive)
    float lo[6], mi[6], hi[6];
    #pragma unroll
    for (int j = 0; j < 6; ++j) {
      const float plo = fminf(b[j], c[j]);
      const float phi = fmaxf(b[j], c[j]);
      lo[j] = fminf(a[j], plo);
      hi[j] = fmaxf(a[j], phi);
      mi[j] = fmaxf(plo, fminf(a[j], phi));
    }

    f32x4 o;
    #pragma unroll
    for (int i = 0; i < 4; ++i) {
      const float mxlo = fmaxf(fmaxf(lo[i], lo[i + 1]), lo[i + 2]);
      const float mnhi = fminf(fminf(hi[i], hi[i + 1]), hi[i + 2]);
      const float mdmi = med3(mi[i], mi[i + 1], mi[i + 2]);
      o[i] = med3(mxlo, mdmi, mnhi);
    }
    __builtin_nontemporal_store(o,
        reinterpret_cast<f32x4*>(q + (size_t)y * W + x0));
  }
}

extern "C" void kernel_launch(void* const* d_in, const int* in_sizes, int n_in,
                              void* d_out, int out_size, void* d_ws, size_t ws_size,
                              hipStream_t stream) {
  const float* x = (const float*)d_in[0];
  float* out = (float*)d_out;

  const int H = 1024, W = 1024;
  const int planes = in_sizes[0] / (H * W);   // B*C = 12
  const int tiles_per_plane = H / R;          // 64
  const int nblocks = planes * tiles_per_plane;  // 768 (divisible by 8)
  const int chunk = nblocks / NXCD;           // 96

  dim3 grid(nblocks);
  dim3 block(W / 4);  // 256 threads, 4 px each
  median3x3_kernel<<<grid, block, 0, stream>>>(x, out, H, W,
                                               tiles_per_plane, chunk);
}

// Round 5
// 21.186 us; speedup vs baseline: 1.8864x; 1.0397x over previous
//
#include <hip/hip_runtime.h>

// 3x3 median filter, reflect padding, fp32, NCHW (4,3,1024,1024).
// 256 threads = full 1024-wide row (4 px/thread as float4); each block
// computes R=8 consecutive rows (1536 blocks -> 24 waves/CU for latency
// hiding) via a 4-slot register rolling window, software-pipelined so the
// load of row r+2 is issued BEFORE computing row r (load->use distance =
// one full iteration). Halos via __shfl inside the wave.
// XCD-chunked block swizzle keeps vertically-adjacent blocks on the same
// XCD L2; nontemporal stores keep the write stream out of L2.
// Median-of-9 = column decomposition: med3(max3(lo), med3(mi), min3(hi)).

constexpr int R = 8;
constexpr int NXCD = 8;

typedef float f32x4 __attribute__((ext_vector_type(4)));

__device__ __forceinline__ float med3(float a, float b, float c) {
  return __builtin_amdgcn_fmed3f(a, b, c);
}

__global__ __launch_bounds__(256) void median3x3_kernel(
    const float* __restrict__ in, float* __restrict__ out, int H, int W,
    int tiles_per_plane, int chunk) {
  const int wg  = blockIdx.x;
  const int swz = (wg & (NXCD - 1)) * chunk + (wg >> 3);
  const int plane = swz / tiles_per_plane;
  const int y0    = (swz % tiles_per_plane) * R;

  const int tid  = threadIdx.x;
  const int x0   = tid * 4;
  const int lane = tid & 63;

  const float* p = in  + (size_t)plane * H * W;
  float*       q = out + (size_t)plane * H * W;

  float rows[4][6];  // 4-slot rolling window: [left_halo, m0..m3, right_halo]

  auto load_row = [&](int y, float (&v)[6]) {
    const float* rp = p + (size_t)y * W;
    const float4 m = *reinterpret_cast<const float4*>(rp + x0);
    float lh = __shfl_up(m.w, 1);    // left neighbor's last px
    float rh = __shfl_down(m.x, 1);  // right neighbor's first px
    if (lane == 0)  lh = (x0 == 0)     ? m.y : rp[x0 - 1];  // reflect / cross-wave
    if (lane == 63) rh = (x0 + 4 >= W) ? m.z : rp[x0 + 4];
    v[0] = lh; v[1] = m.x; v[2] = m.y; v[3] = m.z; v[4] = m.w; v[5] = rh;
  };

  // prime: 3 independent loads in flight (rows y0-1, y0, y0+1; reflect -1 -> 1)
  load_row(y0 == 0 ? 1 : y0 - 1, rows[0]);
  load_row(y0, rows[1]);
  load_row(y0 + 1 >= H ? H - 2 : y0 + 1, rows[2]);

  #pragma unroll
  for (int r = 0; r < R; ++r) {
    // issue next-next row load first (consumed at iter r+1)
    if (r < R - 1) {
      int y2 = y0 + r + 2;
      y2 = (y2 >= H) ? 2 * H - 2 - y2 : y2;  // reflect: H -> H-2
      load_row(y2, rows[(r + 3) % 4]);
    }

    const float (&a)[6] = rows[r % 4];
    const float (&b)[6] = rows[(r + 1) % 4];
    const float (&c)[6] = rows[(r + 2) % 4];

    // per-column sorted vertical triple (non-destructive)
    float lo[6], mi[6], hi[6];
    #pragma unroll
    for (int j = 0; j < 6; ++j) {
      const float plo = fminf(b[j], c[j]);
      const float phi = fmaxf(b[j], c[j]);
      lo[j] = fminf(a[j], plo);
      hi[j] = fmaxf(a[j], phi);
      mi[j] = fmaxf(plo, fminf(a[j], phi));
    }

    f32x4 o;
    #pragma unroll
    for (int i = 0; i < 4; ++i) {
      const float mxlo = fmaxf(fmaxf(lo[i], lo[i + 1]), lo[i + 2]);
      const float mnhi = fminf(fminf(hi[i], hi[i + 1]), hi[i + 2]);
      const float mdmi = med3(mi[i], mi[i + 1], mi[i + 2]);
      o[i] = med3(mxlo, mdmi, mnhi);
    }
    __builtin_nontemporal_store(o,
        reinterpret_cast<f32x4*>(q + (size_t)(y0 + r) * W + x0));
  }
}

extern "C" void kernel_launch(void* const* d_in, const int* in_sizes, int n_in,
                              void* d_out, int out_size, void* d_ws, size_t ws_size,
                              hipStream_t stream) {
  const float* x = (const float*)d_in[0];
  float* out = (float*)d_out;

  const int H = 1024, W = 1024;
  const int planes = in_sizes[0] / (H * W);      // B*C = 12
  const int tiles_per_plane = H / R;             // 128
  const int nblocks = planes * tiles_per_plane;  // 1536 (divisible by 8)
  const int chunk = nblocks / NXCD;              // 192

  dim3 grid(nblocks);
  dim3 block(W / 4);  // 256 threads, 4 px each
  median3x3_kernel<<<grid, block, 0, stream>>>(x, out, H, W,
                                               tiles_per_plane, chunk);
}